// Round 10
// baseline (1587.235 us; speedup 1.0000x reference)
//
#include <hip/hip_runtime.h>

#define BATCH 64
#define TIN   49
#define NB    24
#define HID   384
#define SOUT  10
#define NGATE 5

typedef __attribute__((ext_vector_type(4))) float f32x4;
typedef __attribute__((ext_vector_type(8))) short short8v;

__device__ __forceinline__ unsigned short f2bf(float f) {
    union { float f; unsigned u; } v; v.f = f;
    unsigned r = v.u + 0x7fffu + ((v.u >> 16) & 1u);   // round-nearest-even
    return (unsigned short)(r >> 16);
}
__device__ __forceinline__ float bf2f(unsigned short h) {
    union { unsigned u; float f; } v; v.u = ((unsigned)h) << 16; return v.f;
}

#define NW3_BLK 4320    // 48 cells * 5 gates * 3 mats * 6 kb(64-row spans)
#define NP_BLK  23040
#define NM_BLK  576

// ---------------------------------------------------------------------------
// Fused prologue: pack_w (sequential-stream + LDS transpose) + pack_p +
// init_means. wpack layout (short8 units):
//   [(cell*12+t32)*5+g][kc=36][pair=2][lane=64]
//   kc = m*12 + kb*2 + kc2; elem jj: B[k][col], k = kc*32+(lane>>4)*8+jj
//   (within source m), col = t32*32 + pair*16 + (lane&15).
// ---------------------------------------------------------------------------
__global__ __launch_bounds__(256) void prologue_kernel(
    const float* __restrict__ U, const float* __restrict__ Wt,
    const float* __restrict__ Ws, const float* __restrict__ p,
    const float* __restrict__ hid, const float* __restrict__ cel,
    const float* __restrict__ gt,
    unsigned short* __restrict__ wpack, unsigned short* __restrict__ pb,
    unsigned short* __restrict__ hp_b, float* __restrict__ cp_f)
{
    __shared__ unsigned short tile[64][390];   // stride 195 dwords, gcd(195,32)=1
    int bx = blockIdx.x;
    if (bx < NW3_BLK) {
        int q = bx;
        int kb = q % 6; q /= 6;
        int m  = q % 3; q /= 3;
        int g  = q % 5; q /= 5;
        int cell = q;                                  // 0..47 (r*NB+n)
        const float* W = (m == 0) ? U : (m == 1) ? Wt : Ws;
        const float* src = W + ((size_t)(cell * NGATE + g) * HID + kb * 64) * HID;
        int tid = threadIdx.x;
        // ---- read 64x384 f32 fully sequential (96 KB), convert to bf16 tile
        //      6144 float4 chunks / 256 threads = 24 per thread  (r9 bug: was 6)
#pragma unroll
        for (int i = 0; i < 24; ++i) {
            int c = tid + i * 256;
            int row = c / 96, c4 = (c % 96) * 4;       // 96 float4 per row
            float4 v = *(const float4*)(src + (size_t)row * HID + c4);
            tile[row][c4 + 0] = f2bf(v.x);
            tile[row][c4 + 1] = f2bf(v.y);
            tile[row][c4 + 2] = f2bf(v.z);
            tile[row][c4 + 3] = f2bf(v.w);
        }
        __syncthreads();
        // ---- gather 48 fragment-units (1 KB each), coalesced writes
        int lane = tid & 63, grp = tid >> 6;
#pragma unroll
        for (int uu = 0; uu < 12; ++uu) {
            int unit = grp * 12 + uu;                  // 0..47
            int pair = unit & 1, kc2 = (unit >> 1) & 1, t32 = unit >> 2;
            int kl = kc2 * 32 + (lane >> 4) * 8;
            int cl = t32 * 32 + pair * 16 + (lane & 15);
            unsigned short o[8];
#pragma unroll
            for (int jj = 0; jj < 8; ++jj) o[jj] = tile[kl + jj][cl];
            int kc = m * 12 + kb * 2 + kc2;
            size_t dst = ((size_t)((cell * 12 + t32) * NGATE + g) * 72
                          + kc * 2 + pair) * 64 + lane;
            *(short8v*)(wpack + dst * 8) = *(const short8v*)o;
        }
    } else if (bx < NW3_BLK + NP_BLK) {
        // p f32 [B][SOUT][NB][H] -> bf16 [SOUT][NB][B][H]
        size_t idx = (size_t)(bx - NW3_BLK) * 256 + threadIdx.x;  // 5,898,240
        int h = (int)(idx % HID);
        size_t q = idx / HID;
        int b = (int)(q % BATCH); q /= BATCH;
        int n = (int)(q % NB); q /= NB;
        int f = (int)q;
        pb[idx] = f2bf(p[((size_t)(b * SOUT + f) * NB + n) * HID + h]);
    } else {
        // temporal means -> hp (bf16) + cp (f32), layout [r][n][b][h]
        int idx = (bx - NW3_BLK - NP_BLK) * 256 + threadIdx.x;    // 147,456
        const int total4 = NB * BATCH * HID / 4;
        if (idx >= total4) return;
        const int H4 = HID / 4;
        int h = (idx % H4) * 4;
        int b = (idx / H4) % BATCH;
        int n = idx / (H4 * BATCH);
        const int fs4 = NB * HID / 4;
        const float4* ph = (const float4*)(hid + ((size_t)b * TIN * NB + n) * HID + h);
        const float4* pc = (const float4*)(cel + ((size_t)b * TIN * NB + n) * HID + h);
        float sh[4] = {0,0,0,0}, sc[4] = {0,0,0,0};
        for (int t = 0; t < TIN; ++t) {
            float4 vh = ph[(size_t)t * fs4];
            float4 vc = pc[(size_t)t * fs4];
            sh[0] += vh.x; sh[1] += vh.y; sh[2] += vh.z; sh[3] += vh.w;
            sc[0] += vc.x; sc[1] += vc.y; sc[2] += vc.z; sc[3] += vc.w;
        }
        float4 g4 = *(const float4*)(gt + ((size_t)b * NB + n) * HID + h);
        const float* g_ = (const float*)&g4;
        unsigned short o0[4], o1[4];
        float c0[4];
#pragma unroll
        for (int j = 0; j < 4; ++j) {
            o0[j] = f2bf(sh[j] / TIN);
            o1[j] = f2bf((g_[j] + sh[j]) / (TIN + 1));
            c0[j] = sc[j] / TIN;
        }
        size_t base = (size_t)idx * 4;
        const size_t tot = (size_t)NB * BATCH * HID;
        *(uint2*)(hp_b + base)       = *(const uint2*)o0;
        *(uint2*)(hp_b + tot + base) = *(const uint2*)o1;
        *(float4*)(cp_f + base)       = make_float4(c0[0], c0[1], c0[2], c0[3]);
        *(float4*)(cp_f + tot + base) = make_float4(c0[0], c0[1], c0[2], c0[3]);
    }
}

// spatial boundary: mean over bones of the r=0 init states
__global__ void init_bounds_kernel(const unsigned short* __restrict__ hp_b,
                                   const float* __restrict__ cp_f,
                                   unsigned short* __restrict__ bh_b,
                                   float* __restrict__ bc_f) {
    int idx = blockIdx.x * blockDim.x + threadIdx.x;       // BATCH*HID
    if (idx >= BATCH * HID) return;
    float sh = 0.f, sc = 0.f;
    for (int n = 0; n < NB; ++n) {
        sh += bf2f(hp_b[(size_t)n * BATCH * HID + idx]);
        sc += cp_f[(size_t)n * BATCH * HID + idx];
    }
    bh_b[idx] = f2bf(sh / NB);
    bc_f[idx] = sc / NB;
}

// ---------------------------------------------------------------------------
// Fused wavefront kernel (dispatch d = r0 cells diag d + r1 cells diag d-1).
// grid.x = 12 (32-col tiles), grid.y = A0+A1. Block 640 = 10 waves
// (gate = wv%5, kh = wv/5). A tiles staged in LDS (reg-split load/write),
// shared by all 10 waves. Deep B-prefetch: each phase's full 12-fragment
// weight slice loaded one phase ahead into register banks Ba/Bb.
// ---------------------------------------------------------------------------
union SMem {
    unsigned short A[2][64][392];        // padded: 2-way banks (free)
    float gl[2][NGATE][64][35];          // stride 35 coprime 32 -> 2-way
};

__global__ __launch_bounds__(640) void cell_fused_kernel(
    int d, int A0,
    const unsigned short* __restrict__ pb,
    const unsigned short* __restrict__ wpack,
    const float* __restrict__ bias,
    const unsigned short* __restrict__ hp_b,
    const float* __restrict__ cp_f,
    const unsigned short* __restrict__ bh_b,
    const float* __restrict__ bc_f,
    unsigned short* __restrict__ h_sl,   // [par][r][NB][64][384] bf16
    float* __restrict__ c_sl,            // same shape f32
    float* __restrict__ out)
{
    __shared__ SMem sm;

    int y = blockIdx.y;
    int rstep, dg;
    if (y < A0) { rstep = 0; dg = d; }
    else        { rstep = 1; dg = d - 1; y -= A0; }
    int lo = dg - (SOUT - 1); if (lo < 0) lo = 0;
    const int n = lo + y;
    const int f = dg - n;
    const int cur = dg & 1, prv = cur ^ 1;
    const int t = blockIdx.x;            // 32-col tile, 0..11
    const int wv   = threadIdx.x >> 6;
    const int gate = wv % NGATE;
    const int kh   = wv / NGATE;
    const int lane = threadIdx.x & 63;
    const int S = BATCH * HID;
    const int cell = rstep * NB + n;

    const unsigned short *xb, *htb, *hsb;
    const float *ctb, *csb;
    if (rstep == 0) {
        xb  = pb + (size_t)(f * NB + n) * S;
        htb = f ? h_sl + (size_t)((prv * 2 + 0) * NB + n) * S : hp_b + (size_t)n * S;
        hsb = n ? h_sl + (size_t)((prv * 2 + 0) * NB + n - 1) * S : bh_b;
        ctb = f ? c_sl + (size_t)((prv * 2 + 0) * NB + n) * S : cp_f + (size_t)n * S;
        csb = n ? c_sl + (size_t)((prv * 2 + 0) * NB + n - 1) * S : bc_f;
    } else {
        xb  = h_sl + (size_t)((cur * 2 + 0) * NB + n) * S;   // h0 of this cell
        htb = f ? h_sl + (size_t)((prv * 2 + 1) * NB + n) * S
                : hp_b + (size_t)(NB + n) * S;
        hsb = n ? h_sl + (size_t)((prv * 2 + 1) * NB + n - 1) * S : bh_b;
        ctb = f ? c_sl + (size_t)((prv * 2 + 1) * NB + n) * S
                : cp_f + (size_t)(NB + n) * S;
        csb = n ? c_sl + (size_t)((prv * 2 + 1) * NB + n - 1) * S : bc_f;
    }

    const short8v* wp = (const short8v*)wpack
        + (size_t)((cell * 12 + t) * NGATE + gate) * (36 * 2 * 64);

    // ---- deep B-prefetch banks (static indexing; 96 VGPR)
    short8v Ba[12], Bb[12];
    auto LOADB = [&](short8v* B, int m) {
#pragma unroll
        for (int u = 0; u < 12; ++u) {
            int j = u >> 1, pair = u & 1;
            B[u] = wp[(size_t)(((m * 12 + kh * 6 + j) * 2) + pair) * 64 + lane];
        }
    };

    // ---- hoist epilogue cell-state loads (latency hides under MFMA)
    const int eb = threadIdx.x & 63;
    const int ecq = (threadIdx.x >> 6) & 3;
    float4 cth[2], csh[2];
    if (threadIdx.x < 256) {
#pragma unroll
        for (int h = 0; h < 2; ++h) {
            int colg = t * 32 + h * 16 + ecq * 4;
            cth[h] = *(const float4*)(ctb + (size_t)eb * HID + colg);
            csh[h] = *(const float4*)(csb + (size_t)eb * HID + colg);
        }
    }

    // ---- staging machinery: 64x384 bf16 = 3072 16B-chunks, 640 threads
    uint4 streg[5];
    auto STAGE_LOAD = [&](const unsigned short* src) {
#pragma unroll
        for (int i = 0; i < 5; ++i) {
            int c = (int)threadIdx.x + i * 640;
            if (i < 4 || c < 3072) {
                int row = c / 48, cc = c - row * 48;
                streg[i] = *(const uint4*)(src + (size_t)row * HID + cc * 8);
            }
        }
    };
    auto STAGE_WRITE = [&](int buf) {
#pragma unroll
        for (int i = 0; i < 5; ++i) {
            int c = (int)threadIdx.x + i * 640;
            if (i < 4 || c < 3072) {
                int row = c / 48, cc = c - row * 48;
                *(uint4*)&sm.A[buf][row][cc * 8] = streg[i];
            }
        }
    };

    f32x4 acc[2][4];
#pragma unroll
    for (int pr = 0; pr < 2; ++pr)
#pragma unroll
        for (int q = 0; q < 4; ++q) acc[pr][q] = (f32x4){0, 0, 0, 0};

    const int arow = lane & 15;
    const int akg  = (lane >> 4) * 8;

    auto COMPUTE = [&](int buf, const short8v* B) {
#pragma unroll
        for (int j = 0; j < 6; ++j) {
            const int koff = kh * 192 + j * 32 + akg;
            short8v a[4];
#pragma unroll
            for (int q = 0; q < 4; ++q)
                a[q] = *(const short8v*)&sm.A[buf][arow + q * 16][koff];
#pragma unroll
            for (int q = 0; q < 4; ++q) {
                acc[0][q] = __builtin_amdgcn_mfma_f32_16x16x32_bf16(a[q], B[2 * j],     acc[0][q], 0, 0, 0);
                acc[1][q] = __builtin_amdgcn_mfma_f32_16x16x32_bf16(a[q], B[2 * j + 1], acc[1][q], 0, 0, 0);
            }
        }
    };

    // ---- pipeline: weights one phase ahead, A one source ahead
    LOADB(Ba, 0);
    STAGE_LOAD(xb);
    STAGE_WRITE(0);
    __syncthreads();

    STAGE_LOAD(htb);
    LOADB(Bb, 1);
    COMPUTE(0, Ba);
    __syncthreads();
    STAGE_WRITE(1);
    __syncthreads();

    STAGE_LOAD(hsb);
    LOADB(Ba, 2);
    COMPUTE(1, Bb);
    __syncthreads();
    STAGE_WRITE(0);
    __syncthreads();

    COMPUTE(0, Ba);
    __syncthreads();                     // A reads done; gl may alias A

    // ---- gate exchange
#pragma unroll
    for (int pr = 0; pr < 2; ++pr)
#pragma unroll
        for (int q = 0; q < 4; ++q)
#pragma unroll
            for (int i = 0; i < 4; ++i)
                sm.gl[kh][gate][q * 16 + (lane >> 4) * 4 + i][pr * 16 + (lane & 15)]
                    = acc[pr][q][i];
    __syncthreads();

    // ---- fused epilogue (256 threads, b = tid&63 -> stride-35 reads, 2-way)
    if (threadIdx.x < 256) {
        size_t dbase = (size_t)((cur * 2 + rstep) * NB + n) * S + (size_t)eb * HID;
        const float* bbase = bias + (size_t)cell * NGATE * HID;
#pragma unroll
        for (int h = 0; h < 2; ++h) {
            int cloc = h * 16 + ecq * 4;
            int colg = t * 32 + cloc;
            const float* ct_ = (const float*)&cth[h];
            const float* cs_ = (const float*)&csh[h];
            float hv4[4], ch4[4];
            unsigned short hb4[4];
#pragma unroll
            for (int cc = 0; cc < 4; ++cc) {
                float gi  = sm.gl[0][0][eb][cloc + cc] + sm.gl[1][0][eb][cloc + cc] + bbase[0 * HID + colg + cc];
                float gfs = sm.gl[0][1][eb][cloc + cc] + sm.gl[1][1][eb][cloc + cc] + bbase[1 * HID + colg + cc];
                float gft = sm.gl[0][2][eb][cloc + cc] + sm.gl[1][2][eb][cloc + cc] + bbase[2 * HID + colg + cc];
                float go  = sm.gl[0][3][eb][cloc + cc] + sm.gl[1][3][eb][cloc + cc] + bbase[3 * HID + colg + cc];
                float gc  = sm.gl[0][4][eb][cloc + cc] + sm.gl[1][4][eb][cloc + cc] + bbase[4 * HID + colg + cc];
                float i_n = 1.f / (1.f + __expf(-gi));
                float f_s = 1.f / (1.f + __expf(-gfs));
                float f_t = 1.f / (1.f + __expf(-gft));
                float o_n = 1.f / (1.f + __expf(-go));
                float c_n = tanhf(gc);
                float ch  = i_n * c_n + f_t * ct_[cc] + f_s * cs_[cc];
                float hv  = o_n * tanhf(ch);
                hv4[cc] = hv; ch4[cc] = ch; hb4[cc] = f2bf(hv);
            }
            *(uint2*)(h_sl + dbase + colg) = *(const uint2*)hb4;
            *(float4*)(c_sl + dbase + colg) = make_float4(ch4[0], ch4[1], ch4[2], ch4[3]);
            if (rstep == 1) {
                size_t o = ((size_t)(eb * SOUT + f) * NB + n) * HID + colg;
                *(float4*)(out + o) = make_float4(hv4[0], hv4[1], hv4[2], hv4[3]);
                *(float4*)(out + (size_t)BATCH * SOUT * NB * HID + o)
                    = make_float4(ch4[0], ch4[1], ch4[2], ch4[3]);
            }
        }
    }
}

// ---------------------------------------------------------------------------
extern "C" void kernel_launch(void* const* d_in, const int* in_sizes, int n_in,
                              void* d_out, int out_size, void* d_ws, size_t ws_size,
                              hipStream_t stream) {
    const float* hid  = (const float*)d_in[0];
    const float* cel  = (const float*)d_in[1];
    const float* gt   = (const float*)d_in[2];
    // d_in[3] global_s_state: unused by the reference
    const float* p    = (const float*)d_in[4];
    const float* U    = (const float*)d_in[5];
    const float* Wt   = (const float*)d_in[6];
    const float* Ws   = (const float*)d_in[7];
    const float* bias = (const float*)d_in[8];
    float* out = (float*)d_out;

    char* cur_ = (char*)d_ws;
    auto carve = [&](size_t bytes) -> void* {
        void* r = cur_; cur_ += (bytes + 255) & ~(size_t)255; return r;
    };
    const size_t NPBH = (size_t)NB * BATCH * HID;
    unsigned short* wpack = (unsigned short*)carve((size_t)13271040 * 16); // 212 MB
    unsigned short* pb    = (unsigned short*)carve((size_t)SOUT * NB * BATCH * HID * 2);
    unsigned short* hp_b  = (unsigned short*)carve(2 * NPBH * 2);
    float*          cp_f  = (float*)carve(2 * NPBH * 4);
    unsigned short* bh_b  = (unsigned short*)carve((size_t)BATCH * HID * 2);
    float*          bc_f  = (float*)carve((size_t)BATCH * HID * 4);
    unsigned short* h_sl  = (unsigned short*)carve(4 * NPBH * 2);
    float*          c_sl  = (float*)carve(4 * NPBH * 4);

    prologue_kernel<<<NW3_BLK + NP_BLK + NM_BLK, 256, 0, stream>>>(
        U, Wt, Ws, p, hid, cel, gt, wpack, pb, hp_b, cp_f);
    init_bounds_kernel<<<(BATCH * HID + 255) / 256, 256, 0, stream>>>(
        hp_b, cp_f, bh_b, bc_f);

    auto cnt = [](int dg) {
        int lo = dg - (SOUT - 1); if (lo < 0) lo = 0;
        int hi = (dg < NB - 1) ? dg : NB - 1;
        return hi - lo + 1;
    };
    for (int d = 0; d < SOUT + NB; ++d) {          // 34 dispatches
        int A0 = (d <= SOUT + NB - 2) ? cnt(d) : 0;
        int A1 = (d >= 1) ? cnt(d - 1) : 0;
        dim3 grid(12, A0 + A1);
        cell_fused_kernel<<<grid, 640, 0, stream>>>(d, A0, pb, wpack, bias,
                                                    hp_b, cp_f, bh_b, bc_f,
                                                    h_sl, c_sl, out);
    }
}

// Round 11
// 1248.743 us; speedup vs baseline: 1.2711x; 1.2711x over previous
//
#include <hip/hip_runtime.h>

#define BATCH 64
#define TIN   49
#define NB    24
#define HID   384
#define SOUT  10
#define NGATE 5

typedef __attribute__((ext_vector_type(4))) float f32x4;
typedef __attribute__((ext_vector_type(8))) short short8v;

__device__ __forceinline__ unsigned short f2bf(float f) {
    union { float f; unsigned u; } v; v.f = f;
    unsigned r = v.u + 0x7fffu + ((v.u >> 16) & 1u);   // round-nearest-even
    return (unsigned short)(r >> 16);
}
__device__ __forceinline__ float bf2f(unsigned short h) {
    union { unsigned u; float f; } v; v.u = ((unsigned)h) << 16; return v.f;
}

#define NW3_BLK 4320    // 48 cells * 5 gates * 3 mats * 6 kb(64-row spans)
#define NP_BLK  23040
#define NM_BLK  576

// ---------------------------------------------------------------------------
// Fused prologue: pack_w (sequential-stream + LDS transpose) + pack_p +
// init_means. wpack layout (short8 units):
//   [(cell*12+t32)*5+g][kc=36][pair=2][lane=64]
//   kc = m*12 + kb*2 + kc2; elem jj: B[k][col], k = kc%12*32+(lane>>4)*8+jj
//   within source m, col = t32*32 + pair*16 + (lane&15).
// ---------------------------------------------------------------------------
__global__ __launch_bounds__(256) void prologue_kernel(
    const float* __restrict__ U, const float* __restrict__ Wt,
    const float* __restrict__ Ws, const float* __restrict__ p,
    const float* __restrict__ hid, const float* __restrict__ cel,
    const float* __restrict__ gt,
    unsigned short* __restrict__ wpack, unsigned short* __restrict__ pb,
    unsigned short* __restrict__ hp_b, float* __restrict__ cp_f)
{
    __shared__ unsigned short tile[64][390];   // stride 195 dwords, gcd(195,32)=1
    int bx = blockIdx.x;
    if (bx < NW3_BLK) {
        int q = bx;
        int kb = q % 6; q /= 6;
        int m  = q % 3; q /= 3;
        int g  = q % 5; q /= 5;
        int cell = q;                                  // 0..47 (r*NB+n)
        const float* W = (m == 0) ? U : (m == 1) ? Wt : Ws;
        const float* src = W + ((size_t)(cell * NGATE + g) * HID + kb * 64) * HID;
        int tid = threadIdx.x;
        // ---- read 64x384 f32 fully sequential (96 KB), convert to bf16 tile
#pragma unroll
        for (int i = 0; i < 24; ++i) {
            int c = tid + i * 256;
            int row = c / 96, c4 = (c % 96) * 4;       // 96 float4 per row
            float4 v = *(const float4*)(src + (size_t)row * HID + c4);
            tile[row][c4 + 0] = f2bf(v.x);
            tile[row][c4 + 1] = f2bf(v.y);
            tile[row][c4 + 2] = f2bf(v.z);
            tile[row][c4 + 3] = f2bf(v.w);
        }
        __syncthreads();
        // ---- gather 48 fragment-units (1 KB each), coalesced writes
        int lane = tid & 63, grp = tid >> 6;
#pragma unroll
        for (int uu = 0; uu < 12; ++uu) {
            int unit = grp * 12 + uu;                  // 0..47
            int pair = unit & 1, kc2 = (unit >> 1) & 1, t32 = unit >> 2;
            int kl = kc2 * 32 + (lane >> 4) * 8;
            int cl = t32 * 32 + pair * 16 + (lane & 15);
            unsigned short o[8];
#pragma unroll
            for (int jj = 0; jj < 8; ++jj) o[jj] = tile[kl + jj][cl];
            int kc = m * 12 + kb * 2 + kc2;
            size_t dst = ((size_t)((cell * 12 + t32) * NGATE + g) * 72
                          + kc * 2 + pair) * 64 + lane;
            *(short8v*)(wpack + dst * 8) = *(const short8v*)o;
        }
    } else if (bx < NW3_BLK + NP_BLK) {
        // p f32 [B][SOUT][NB][H] -> bf16 [SOUT][NB][B][H]
        size_t idx = (size_t)(bx - NW3_BLK) * 256 + threadIdx.x;  // 5,898,240
        int h = (int)(idx % HID);
        size_t q = idx / HID;
        int b = (int)(q % BATCH); q /= BATCH;
        int n = (int)(q % NB); q /= NB;
        int f = (int)q;
        pb[idx] = f2bf(p[((size_t)(b * SOUT + f) * NB + n) * HID + h]);
    } else {
        // temporal means -> hp (bf16) + cp (f32), layout [r][n][b][h]
        int idx = (bx - NW3_BLK - NP_BLK) * 256 + threadIdx.x;    // 147,456
        const int total4 = NB * BATCH * HID / 4;
        if (idx >= total4) return;
        const int H4 = HID / 4;
        int h = (idx % H4) * 4;
        int b = (idx / H4) % BATCH;
        int n = idx / (H4 * BATCH);
        const int fs4 = NB * HID / 4;
        const float4* ph = (const float4*)(hid + ((size_t)b * TIN * NB + n) * HID + h);
        const float4* pc = (const float4*)(cel + ((size_t)b * TIN * NB + n) * HID + h);
        float sh[4] = {0,0,0,0}, sc[4] = {0,0,0,0};
        for (int t = 0; t < TIN; ++t) {
            float4 vh = ph[(size_t)t * fs4];
            float4 vc = pc[(size_t)t * fs4];
            sh[0] += vh.x; sh[1] += vh.y; sh[2] += vh.z; sh[3] += vh.w;
            sc[0] += vc.x; sc[1] += vc.y; sc[2] += vc.z; sc[3] += vc.w;
        }
        float4 g4 = *(const float4*)(gt + ((size_t)b * NB + n) * HID + h);
        const float* g_ = (const float*)&g4;
        unsigned short o0[4], o1[4];
        float c0[4];
#pragma unroll
        for (int j = 0; j < 4; ++j) {
            o0[j] = f2bf(sh[j] / TIN);
            o1[j] = f2bf((g_[j] + sh[j]) / (TIN + 1));
            c0[j] = sc[j] / TIN;
        }
        size_t base = (size_t)idx * 4;
        const size_t tot = (size_t)NB * BATCH * HID;
        *(uint2*)(hp_b + base)       = *(const uint2*)o0;
        *(uint2*)(hp_b + tot + base) = *(const uint2*)o1;
        *(float4*)(cp_f + base)       = make_float4(c0[0], c0[1], c0[2], c0[3]);
        *(float4*)(cp_f + tot + base) = make_float4(c0[0], c0[1], c0[2], c0[3]);
    }
}

// spatial boundary: mean over bones of the r=0 init states
__global__ void init_bounds_kernel(const unsigned short* __restrict__ hp_b,
                                   const float* __restrict__ cp_f,
                                   unsigned short* __restrict__ bh_b,
                                   float* __restrict__ bc_f) {
    int idx = blockIdx.x * blockDim.x + threadIdx.x;       // BATCH*HID
    if (idx >= BATCH * HID) return;
    float sh = 0.f, sc = 0.f;
    for (int n = 0; n < NB; ++n) {
        sh += bf2f(hp_b[(size_t)n * BATCH * HID + idx]);
        sc += cp_f[(size_t)n * BATCH * HID + idx];
    }
    bh_b[idx] = f2bf(sh / NB);
    bc_f[idx] = sc / NB;
}

// ---------------------------------------------------------------------------
// Fused wavefront kernel (dispatch d = r0 cells diag d + r1 cells diag d-1).
// grid.x = 12 (32-col tiles), grid.y = A0+A1. Block 960 = 15 waves:
// wave w -> gate = w%5, source m = w/5. ALL THREE A-sources staged up-front
// into A[3] (one burst of 12 global loads/thread, ONE barrier), each wave
// computes its source's full K=384 with a rolling 3-slot B window (the r7
// structure that won), writing its own gl[m][gate] plane. 3 barriers total
// (vs 7), 15 waves/CU (vs 10) carrying the B-load concurrency.
// ---------------------------------------------------------------------------
union SMem {
    unsigned short A[3][64][392];        // 150,528 B (<= 160 KiB)
    float gl[3][NGATE][64][35];          // 134,400 B; aliases A after compute
};

__global__ __launch_bounds__(960) void cell_fused_kernel(
    int d, int A0,
    const unsigned short* __restrict__ pb,
    const unsigned short* __restrict__ wpack,
    const float* __restrict__ bias,
    const unsigned short* __restrict__ hp_b,
    const float* __restrict__ cp_f,
    const unsigned short* __restrict__ bh_b,
    const float* __restrict__ bc_f,
    unsigned short* __restrict__ h_sl,   // [par][r][NB][64][384] bf16
    float* __restrict__ c_sl,            // same shape f32
    float* __restrict__ out)
{
    __shared__ SMem sm;

    int y = blockIdx.y;
    int rstep, dg;
    if (y < A0) { rstep = 0; dg = d; }
    else        { rstep = 1; dg = d - 1; y -= A0; }
    int lo = dg - (SOUT - 1); if (lo < 0) lo = 0;
    const int n = lo + y;
    const int f = dg - n;
    const int cur = dg & 1, prv = cur ^ 1;
    const int t = blockIdx.x;            // 32-col tile, 0..11
    const int wv   = threadIdx.x >> 6;
    const int gate = wv % NGATE;
    const int m    = wv / NGATE;         // source 0..2
    const int lane = threadIdx.x & 63;
    const int S = BATCH * HID;
    const int cell = rstep * NB + n;

    const unsigned short *xb, *htb, *hsb;
    const float *ctb, *csb;
    if (rstep == 0) {
        xb  = pb + (size_t)(f * NB + n) * S;
        htb = f ? h_sl + (size_t)((prv * 2 + 0) * NB + n) * S : hp_b + (size_t)n * S;
        hsb = n ? h_sl + (size_t)((prv * 2 + 0) * NB + n - 1) * S : bh_b;
        ctb = f ? c_sl + (size_t)((prv * 2 + 0) * NB + n) * S : cp_f + (size_t)n * S;
        csb = n ? c_sl + (size_t)((prv * 2 + 0) * NB + n - 1) * S : bc_f;
    } else {
        xb  = h_sl + (size_t)((cur * 2 + 0) * NB + n) * S;   // h0 of this cell
        htb = f ? h_sl + (size_t)((prv * 2 + 1) * NB + n) * S
                : hp_b + (size_t)(NB + n) * S;
        hsb = n ? h_sl + (size_t)((prv * 2 + 1) * NB + n - 1) * S : bh_b;
        ctb = f ? c_sl + (size_t)((prv * 2 + 1) * NB + n) * S
                : cp_f + (size_t)(NB + n) * S;
        csb = n ? c_sl + (size_t)((prv * 2 + 1) * NB + n - 1) * S : bc_f;
    }

    const short8v* wp = (const short8v*)wpack
        + (size_t)((cell * 12 + t) * NGATE + gate) * (36 * 2 * 64);
    const short8v* wbm = wp + (size_t)(m * 24) * 64 + lane;   // this wave's source slice

    // ---- hoist epilogue cell-state loads (latency hides under MFMA)
    const int eb = threadIdx.x & 63;
    const int ecq = (threadIdx.x >> 6) & 3;
    float4 cth[2], csh[2];
    if (threadIdx.x < 256) {
#pragma unroll
        for (int h = 0; h < 2; ++h) {
            int colg = t * 32 + h * 16 + ecq * 4;
            cth[h] = *(const float4*)(ctb + (size_t)eb * HID + colg);
            csh[h] = *(const float4*)(csb + (size_t)eb * HID + colg);
        }
    }

    // ---- stage all 3 sources up-front: 3 x 3072 16B-chunks, 960 threads
    const int tid = threadIdx.x;
    uint4 streg[12];
#pragma unroll
    for (int s = 0; s < 3; ++s) {
        const unsigned short* sp = (s == 0) ? xb : (s == 1) ? htb : hsb;
#pragma unroll
        for (int i = 0; i < 4; ++i) {
            int c = tid + i * 960;
            if (i < 3 || c < 3072) {
                int row = c / 48, cc = c - row * 48;
                streg[s * 4 + i] = *(const uint4*)(sp + (size_t)row * HID + cc * 8);
            }
        }
    }
#pragma unroll
    for (int s = 0; s < 3; ++s) {
#pragma unroll
        for (int i = 0; i < 4; ++i) {
            int c = tid + i * 960;
            if (i < 3 || c < 3072) {
                int row = c / 48, cc = c - row * 48;
                *(uint4*)&sm.A[s][row][cc * 8] = streg[s * 4 + i];
            }
        }
    }

    // ---- preload rolling B window (in flight across the barrier)
    short8v bufB[3][2];
#pragma unroll
    for (int j = 0; j < 3; ++j) {
        bufB[j][0] = wbm[(size_t)j * 128];
        bufB[j][1] = wbm[(size_t)j * 128 + 64];
    }
    __syncthreads();                      // barrier 1: A staged

    f32x4 acc[2][4];
#pragma unroll
    for (int pr = 0; pr < 2; ++pr)
#pragma unroll
        for (int q = 0; q < 4; ++q) acc[pr][q] = (f32x4){0, 0, 0, 0};

    const int arow = lane & 15;
    const int akg  = (lane >> 4) * 8;

#pragma unroll
    for (int j = 0; j < 12; ++j) {
        const int koff = j * 32 + akg;
        short8v a[4];
#pragma unroll
        for (int q = 0; q < 4; ++q)
            a[q] = *(const short8v*)&sm.A[m][arow + q * 16][koff];
        const int sl = j % 3;
#pragma unroll
        for (int q = 0; q < 4; ++q) {
            acc[0][q] = __builtin_amdgcn_mfma_f32_16x16x32_bf16(a[q], bufB[sl][0], acc[0][q], 0, 0, 0);
            acc[1][q] = __builtin_amdgcn_mfma_f32_16x16x32_bf16(a[q], bufB[sl][1], acc[1][q], 0, 0, 0);
        }
        if (j < 9) {
            bufB[sl][0] = wbm[(size_t)(j + 3) * 128];
            bufB[sl][1] = wbm[(size_t)(j + 3) * 128 + 64];
        }
    }
    __syncthreads();                      // barrier 2: A reads done; gl may alias

    // ---- gate exchange: each wave owns plane gl[m][gate]
#pragma unroll
    for (int pr = 0; pr < 2; ++pr)
#pragma unroll
        for (int q = 0; q < 4; ++q)
#pragma unroll
            for (int i = 0; i < 4; ++i)
                sm.gl[m][gate][q * 16 + (lane >> 4) * 4 + i][pr * 16 + (lane & 15)]
                    = acc[pr][q][i];
    __syncthreads();                      // barrier 3: planes visible

    // ---- fused epilogue (256 threads)
    if (threadIdx.x < 256) {
        size_t dbase = (size_t)((cur * 2 + rstep) * NB + n) * S + (size_t)eb * HID;
        const float* bbase = bias + (size_t)cell * NGATE * HID;
#pragma unroll
        for (int h = 0; h < 2; ++h) {
            int cloc = h * 16 + ecq * 4;
            int colg = t * 32 + cloc;
            const float* ct_ = (const float*)&cth[h];
            const float* cs_ = (const float*)&csh[h];
            float hv4[4], ch4[4];
            unsigned short hb4[4];
#pragma unroll
            for (int cc = 0; cc < 4; ++cc) {
                int c = cloc + cc;
                float gi  = sm.gl[0][0][eb][c] + sm.gl[1][0][eb][c] + sm.gl[2][0][eb][c] + bbase[0 * HID + colg + cc];
                float gfs = sm.gl[0][1][eb][c] + sm.gl[1][1][eb][c] + sm.gl[2][1][eb][c] + bbase[1 * HID + colg + cc];
                float gft = sm.gl[0][2][eb][c] + sm.gl[1][2][eb][c] + sm.gl[2][2][eb][c] + bbase[2 * HID + colg + cc];
                float go  = sm.gl[0][3][eb][c] + sm.gl[1][3][eb][c] + sm.gl[2][3][eb][c] + bbase[3 * HID + colg + cc];
                float gc  = sm.gl[0][4][eb][c] + sm.gl[1][4][eb][c] + sm.gl[2][4][eb][c] + bbase[4 * HID + colg + cc];
                float i_n = 1.f / (1.f + __expf(-gi));
                float f_s = 1.f / (1.f + __expf(-gfs));
                float f_t = 1.f / (1.f + __expf(-gft));
                float o_n = 1.f / (1.f + __expf(-go));
                float c_n = tanhf(gc);
                float ch  = i_n * c_n + f_t * ct_[cc] + f_s * cs_[cc];
                float hv  = o_n * tanhf(ch);
                hv4[cc] = hv; ch4[cc] = ch; hb4[cc] = f2bf(hv);
            }
            *(uint2*)(h_sl + dbase + colg) = *(const uint2*)hb4;
            *(float4*)(c_sl + dbase + colg) = make_float4(ch4[0], ch4[1], ch4[2], ch4[3]);
            if (rstep == 1) {
                size_t o = ((size_t)(eb * SOUT + f) * NB + n) * HID + colg;
                *(float4*)(out + o) = make_float4(hv4[0], hv4[1], hv4[2], hv4[3]);
                *(float4*)(out + (size_t)BATCH * SOUT * NB * HID + o)
                    = make_float4(ch4[0], ch4[1], ch4[2], ch4[3]);
            }
        }
    }
}

// ---------------------------------------------------------------------------
extern "C" void kernel_launch(void* const* d_in, const int* in_sizes, int n_in,
                              void* d_out, int out_size, void* d_ws, size_t ws_size,
                              hipStream_t stream) {
    const float* hid  = (const float*)d_in[0];
    const float* cel  = (const float*)d_in[1];
    const float* gt   = (const float*)d_in[2];
    // d_in[3] global_s_state: unused by the reference
    const float* p    = (const float*)d_in[4];
    const float* U    = (const float*)d_in[5];
    const float* Wt   = (const float*)d_in[6];
    const float* Ws   = (const float*)d_in[7];
    const float* bias = (const float*)d_in[8];
    float* out = (float*)d_out;

    char* cur_ = (char*)d_ws;
    auto carve = [&](size_t bytes) -> void* {
        void* r = cur_; cur_ += (bytes + 255) & ~(size_t)255; return r;
    };
    const size_t NPBH = (size_t)NB * BATCH * HID;
    unsigned short* wpack = (unsigned short*)carve((size_t)13271040 * 16); // 212 MB
    unsigned short* pb    = (unsigned short*)carve((size_t)SOUT * NB * BATCH * HID * 2);
    unsigned short* hp_b  = (unsigned short*)carve(2 * NPBH * 2);
    float*          cp_f  = (float*)carve(2 * NPBH * 4);
    unsigned short* bh_b  = (unsigned short*)carve((size_t)BATCH * HID * 2);
    float*          bc_f  = (float*)carve((size_t)BATCH * HID * 4);
    unsigned short* h_sl  = (unsigned short*)carve(4 * NPBH * 2);
    float*          c_sl  = (float*)carve(4 * NPBH * 4);

    prologue_kernel<<<NW3_BLK + NP_BLK + NM_BLK, 256, 0, stream>>>(
        U, Wt, Ws, p, hid, cel, gt, wpack, pb, hp_b, cp_f);
    init_bounds_kernel<<<(BATCH * HID + 255) / 256, 256, 0, stream>>>(
        hp_b, cp_f, bh_b, bc_f);

    auto cnt = [](int dg) {
        int lo = dg - (SOUT - 1); if (lo < 0) lo = 0;
        int hi = (dg < NB - 1) ? dg : NB - 1;
        return hi - lo + 1;
    };
    for (int d = 0; d < SOUT + NB; ++d) {          // 34 dispatches
        int A0 = (d <= SOUT + NB - 2) ? cnt(d) : 0;
        int A1 = (d >= 1) ? cnt(d - 1) : 0;
        dim3 grid(12, A0 + A1);
        cell_fused_kernel<<<grid, 960, 0, stream>>>(d, A0, pb, wpack, bias,
                                                    hp_b, cp_f, bh_b, bc_f,
                                                    h_sl, c_sl, out);
    }
}